// Round 11
// baseline (649.581 us; speedup 1.0000x reference)
//
#include <hip/hip_runtime.h>
#include <hip/hip_bf16.h>
#include <stdint.h>

// CubicModel: out = feats(feats(x)@W0^T + b0)@W1^T + b1
// feats(v) = [v, v_i*v_j (i<=j), v^3], d=512, K=132352
//
// R11: producer/consumer wave specialization (AITER-style).
//  768 thr = 12 waves: 8 consumers (MFMA only, 4m x 2n, 64x64 wave tiles)
//  + 4 producers (stage A-features + B-weights for tile t+1).
//  One __syncthreads per K-step: consumers eat buf[t&1] while producers
//  fill buf[(t+1)&1] -> phase costs become max() instead of sum().
//  (R6/R9/R10 post-mortems: step cost ~15-18K cyc is a latency-serialized
//   phase chain, invariant to tile size; all-waves-lockstep never overlaps.)
//  launch_bounds(768,3) -> 170-reg cap: no 128-cap spill trap.

#define D_IN      512
#define BATCH     512
#define K_TOT     132352
#define QUAD_BASE 512
#define CUBE_BASE 131840
#define BM        256
#define BN        128
#define BK        64          // LDS row = 128 B
// LDS layout (dynamic, 96KB): A0 @0, A1 @32K, B0 @64K, B1 @80K
#define A_OFF(buf) ((buf) * 32768u)
#define B_OFF(buf) (65536u + (buf) * 16384u)

typedef __attribute__((ext_vector_type(8))) __bf16 bf16x8;
typedef __attribute__((ext_vector_type(4))) float  f32x4;

__device__ __forceinline__ bf16x8 pack8(float a0, float a1, float a2, float a3,
                                        float a4, float a5, float a6, float a7) {
    bf16x8 r;
    r[0] = (__bf16)a0; r[1] = (__bf16)a1; r[2] = (__bf16)a2; r[3] = (__bf16)a3;
    r[4] = (__bf16)a4; r[5] = (__bf16)a5; r[6] = (__bf16)a6; r[7] = (__bf16)a7;
    return r;
}

// quad feature index: q -> (i,j), i<=j<512, q = i*(1025-i)/2 + (j-i)
__device__ __forceinline__ void decode_quad(int q, int& oi, int& oj) {
    // disc = 1050625-8q = (1025-2i)^2 at row starts; both < 2^24 -> exact
    float s = sqrtf((float)(1050625 - 8 * q));
    int i = (int)((1025.0f - s) * 0.5f);
    i = i < 0 ? 0 : (i > 511 ? 511 : i);
    while (i < 511 && (i + 1) * (1025 - (i + 1)) / 2 <= q) ++i;
    while (i > 0 && i * (1025 - i) / 2 > q) --i;
    oi = i; oj = i + (q - i * (1025 - i) / 2);
}

// Producer staging of one K-tile (A 256x64 feats + B 128x64 W-cast), done by
// 4 waves (ptid in [0,256)).
//  A: chunk c=ptid&7, rows r0+32*i (r0=ptid>>3, i<8); (r&7) i-invariant.
//  B: row rb=ptid&127, chunks (ptid>>7)*4 + j (j<4); W loads issued FIRST
//     (HBM latency hides under the A work).
__device__ __forceinline__ void stage_tile(const float* __restrict__ X, int m0,
                                           const float* __restrict__ W, int n0,
                                           uint8_t* __restrict__ Ab,
                                           uint8_t* __restrict__ Bb,
                                           int kw, int ptid)
{
    // ---- B: issue 8 float4 loads now ----
    const int rb   = ptid & 127;
    const int cb0  = (ptid >> 7) * 4;
    const float* const wrow = W + (size_t)(n0 + rb) * K_TOT + kw + cb0 * 8;
    float4 wb[4][2];
    #pragma unroll
    for (int j = 0; j < 4; ++j) {
        wb[j][0] = *(const float4*)(wrow + j * 8);
        wb[j][1] = *(const float4*)(wrow + j * 8 + 4);
    }

    // ---- A: 8 granules, streamed ----
    const int c  = ptid & 7;
    const int r0 = ptid >> 3;                  // 0..31
    const int k  = kw + c * 8;
    uint8_t* const wp0 = Ab + (size_t)r0 * 128 + (uint32_t)((c ^ (r0 & 7)) * 16);
    const float* const xr = X + (size_t)(m0 + r0) * D_IN;

    if (kw < QUAD_BASE) {                      // linear window
        #pragma unroll 4
        for (int p = 0; p < 8; ++p) {
            const float* row = xr + (size_t)p * (32 * D_IN);
            float4 a = *(const float4*)(row + k);
            float4 b = *(const float4*)(row + k + 4);
            *(bf16x8*)(wp0 + p * 4096) = pack8(a.x, a.y, a.z, a.w, b.x, b.y, b.z, b.w);
        }
    } else if (kw >= CUBE_BASE) {              // cube window
        const int tt = k - CUBE_BASE;
        #pragma unroll 4
        for (int p = 0; p < 8; ++p) {
            const float* row = xr + (size_t)p * (32 * D_IN);
            float4 a = *(const float4*)(row + tt);
            float4 b = *(const float4*)(row + tt + 4);
            *(bf16x8*)(wp0 + p * 4096) = pack8(
                a.x * a.x * a.x, a.y * a.y * a.y, a.z * a.z * a.z, a.w * a.w * a.w,
                b.x * b.x * b.x, b.y * b.y * b.y, b.z * b.z * b.z, b.w * b.w * b.w);
        }
    } else {                                   // quad window (block-uniform cls)
        const int qw = kw - QUAD_BASE;
        int iw, jw; decode_quad(qw, iw, jw);
        if (jw + 63 <= 511) {                  // whole window inside triu row iw
            const int j0 = jw + c * 8;
            #pragma unroll 4
            for (int p = 0; p < 8; ++p) {
                const float* row = xr + (size_t)p * (32 * D_IN);
                const float xi = row[iw];
                float4 a = *(const float4*)(row + j0);
                float4 b = *(const float4*)(row + j0 + 4);
                *(bf16x8*)(wp0 + p * 4096) = pack8(
                    xi * a.x, xi * a.y, xi * a.z, xi * a.w,
                    xi * b.x, xi * b.y, xi * b.z, xi * b.w);
            }
        } else {
            int ie, je; decode_quad(qw + 63, ie, je);
            if (ie <= 504) {                   // all rows in window have len>=8:
                int i0, j0; decode_quad(qw + c * 8, i0, j0);
                const int s1   = 512 - j0;     // elems in segment A
                const int off1 = i0 + j0 - 511;// segB index base (row i0+1)
                int xx[8];
                #pragma unroll
                for (int e = 0; e < 8; ++e) xx[e] = (e < s1 ? j0 : off1) + e;
                #pragma unroll 2
                for (int p = 0; p < 8; ++p) {
                    const float* row = xr + (size_t)p * (32 * D_IN);
                    const float xa = row[i0];
                    const float xb = row[i0 + 1];      // i0<=504 -> in bounds
                    *(bf16x8*)(wp0 + p * 4096) = pack8(
                        (0 < s1 ? xa : xb) * row[xx[0]], (1 < s1 ? xa : xb) * row[xx[1]],
                        (2 < s1 ? xa : xb) * row[xx[2]], (3 < s1 ? xa : xb) * row[xx[3]],
                        (4 < s1 ? xa : xb) * row[xx[4]], (5 < s1 ? xa : xb) * row[xx[5]],
                        (6 < s1 ? xa : xb) * row[xx[6]], (7 < s1 ? xa : xb) * row[xx[7]]);
                }
            } else {                           // generic tail (1 window/layer)
                int i0, j0; decode_quad(qw + c * 8, i0, j0);
                #pragma unroll 1
                for (int p = 0; p < 8; ++p) {
                    const float* row = xr + (size_t)p * (32 * D_IN);
                    int i = i0, j = j0;
                    float xi = row[i];
                    float v[8];
                    #pragma unroll
                    for (int e = 0; e < 8; ++e) {
                        v[e] = xi * row[j];
                        ++j;
                        if (e < 7 && j == 512) { ++i; j = i; xi = row[i]; }
                    }
                    *(bf16x8*)(wp0 + p * 4096) = pack8(v[0], v[1], v[2], v[3],
                                                       v[4], v[5], v[6], v[7]);
                }
            }
        }
    }

    // ---- B: cvt + swizzled write (loads have had the whole A phase) ----
    uint8_t* const bbase = Bb + (size_t)rb * 128;
    #pragma unroll
    for (int j = 0; j < 4; ++j) {
        *(bf16x8*)(bbase + (uint32_t)(((cb0 + j) ^ (rb & 7)) * 16)) =
            pack8(wb[j][0].x, wb[j][0].y, wb[j][0].z, wb[j][0].w,
                  wb[j][1].x, wb[j][1].y, wb[j][1].z, wb[j][1].w);
    }
}

// ---------------- fused producer/consumer GEMM ----------------
// C[m0:m0+256][ldc] += feats(X)[.][K] * W_f32[n0:n0+128][K]^T (+bias ks==0)
__global__ __launch_bounds__(768, 3) void gemm_pc(
    const float* __restrict__ X,
    const float* __restrict__ W,
    float* __restrict__ C, int ldc,
    const float* __restrict__ bias, int split_steps)
{
    extern __shared__ uint8_t smem[];
    const int tid  = threadIdx.x;
    const int wave = tid >> 6;                 // 0..11
    const int m0   = (blockIdx.x & 1) * BM;
    const int n0   = (blockIdx.x >> 1) * BN;
    const int ks   = blockIdx.y;

    const int kbeg = ks * split_steps * BK;
    const int kend = min(K_TOT, kbeg + split_steps * BK);
    if (kbeg >= kend) return;                  // block-uniform; ks==0 has work
    const int nt = (kend - kbeg) / BK;

    if (wave >= 8) {
        // ================= producer waves (4) =================
        const int ptid = tid - 512;            // 0..255
        stage_tile(X, m0, W, n0, smem + A_OFF(0), smem + B_OFF(0), kbeg, ptid);
        __syncthreads();                       // tile 0 ready
        for (int t = 0; t < nt; ++t) {
            if (t + 1 < nt)
                stage_tile(X, m0, W, n0,
                           smem + A_OFF((t + 1) & 1), smem + B_OFF((t + 1) & 1),
                           kbeg + (t + 1) * BK, ptid);
            __syncthreads();                   // tile t consumed / t+1 ready
        }
        return;                                // no epilogue
    }

    // ================= consumer waves (8) =================
    const int lane = tid & 63;
    const int wm   = wave >> 1;                // 0..3
    const int wn   = wave & 1;                 // 0..1
    const int fr   = lane & 15;
    const int h    = lane >> 4;
    // swizzled frag addressing: row&7 == lane&7 for all fragments; bases for
    // s=0 / s=1 (chunk ^64); mf/nf strides are +2048B immediates.
    const uint32_t cs0 = (uint32_t)((h ^ (lane & 7)) * 16);
    const uint32_t a0 = (uint32_t)(wm * 64 + fr) * 128 + cs0;
    const uint32_t a1 = a0 ^ 64u;
    const uint32_t b0 = (uint32_t)(wn * 64 + fr) * 128 + cs0;
    const uint32_t b1 = b0 ^ 64u;

    f32x4 acc[4][4] = {};
    __syncthreads();                           // tile 0 ready

    for (int t = 0; t < nt; ++t) {
        const uint8_t* const Ab = smem + A_OFF(t & 1);
        const uint8_t* const Bb = smem + B_OFF(t & 1);

        __builtin_amdgcn_s_setprio(1);
        #pragma unroll
        for (int s = 0; s < 2; ++s) {
            const uint32_t ab = s ? a1 : a0;
            const uint32_t bb = s ? b1 : b0;
            bf16x8 a[4];
            #pragma unroll
            for (int mf = 0; mf < 4; ++mf)
                a[mf] = *(const bf16x8*)(Ab + ab + mf * 2048u);
            #pragma unroll
            for (int nf = 0; nf < 4; ++nf) {
                bf16x8 b = *(const bf16x8*)(Bb + bb + nf * 2048u);
                #pragma unroll
                for (int mf = 0; mf < 4; ++mf)
                    acc[mf][nf] = __builtin_amdgcn_mfma_f32_16x16x32_bf16(a[mf], b, acc[mf][nf], 0, 0, 0);
            }
        }
        __builtin_amdgcn_s_setprio(0);
        __syncthreads();                       // done with tile t
    }

    // epilogue: C/D layout col=lane&15, row=(lane>>4)*4+reg  [m89-verified]
    const bool dob = (ks == 0);
    const int rbase = m0 + wm * 64 + (lane >> 4) * 4;
    const int cbase = n0 + wn * 64 + (lane & 15);
    #pragma unroll
    for (int nf = 0; nf < 4; ++nf) {
        const int col = cbase + nf * 16;
        const float bv = dob ? bias[col] : 0.0f;
        #pragma unroll
        for (int mf = 0; mf < 4; ++mf) {
            const int row = rbase + mf * 16;
            #pragma unroll
            for (int r = 0; r < 4; ++r)
                unsafeAtomicAdd(&C[(size_t)(row + r) * ldc + col], acc[mf][nf][r] + bv);
        }
    }
}

// ---------------- host ----------------
extern "C" void kernel_launch(void* const* d_in, const int* in_sizes, int n_in,
                              void* d_out, int out_size, void* d_ws, size_t ws_size,
                              hipStream_t stream)
{
    const float* x  = (const float*)d_in[0];
    const float* W0 = (const float*)d_in[1];
    const float* b0 = (const float*)d_in[2];
    const float* W1 = (const float*)d_in[3];
    const float* b1 = (const float*)d_in[4];
    float* out = (float*)d_out;

    float* hbuf = (float*)d_ws;                        // [512][512]
    const size_t hbytes = (size_t)BATCH * 512 * 4;

    static int lds_set = 0;
    if (!lds_set) {    // host-side, idempotent, outside stream -> capture-safe
        hipFuncSetAttribute((const void*)gemm_pc,
                            hipFuncAttributeMaxDynamicSharedMemorySize, 98304);
        lds_set = 1;
    }

    hipMemsetAsync(hbuf, 0, hbytes, stream);
    hipMemsetAsync(out, 0, (size_t)out_size * 4, stream);

    const int TS = K_TOT / BK;                         // 2068 K-steps total

    // layer 0: 2 m-blocks x 4 n-blocks x 32 ks = 256 blocks (1/CU), nt<=65
    {
        const int ss = 65;
        const int gy = (TS + ss - 1) / ss;             // 32
        gemm_pc<<<dim3(8, gy), 768, 98304, stream>>>(
            x, W0, hbuf, 512, b0, ss);
    }
    // layer 1: 2 m-blocks x 2 n-blocks x 63 ks = 252 blocks, nt<=33
    {
        const int ss = 33;
        const int gy = (TS + ss - 1) / ss;             // 63
        gemm_pc<<<dim3(4, gy), 768, 98304, stream>>>(
            hbuf, W1, out, 256, b1, ss);
    }
}